// Round 4
// baseline (958.024 us; speedup 1.0000x reference)
//
#include <hip/hip_runtime.h>

// (32, 3, 384, 640) fp32 in, (32, 1, 384, 640) fp32 out.
// v5: LDS-free register stencil. v2-v4 showed the stage->barrier->compute
// convoy is the bottleneck (nothing saturated: VALU 40%, HBM 27%, LDS 25%,
// occ 34%; ILP restructure was a no-op). A 3x3 stencil's halo fits in
// registers: each thread computes ONE output row x 4 px, loading
// 3 rows x 2 tensors x (float4 + 2 scalar) directly from global. Vertical
// overlap between thread rows is L1/L2-served (block working set ~10KB/ch).
//   - zero __syncthreads, zero LDS -> occupancy cap 8 blocks/CU (32 waves).
//   - __launch_bounds__(256,8) pins VGPR <= 64 to actually reach 32 waves.
//   - reflection: the only reflected columns are inside the lane's own
//     float4 (reflect(-1)=1 -> xm.y at c0=0; reflect(640)=638 -> xm.z at
//     c0=636) -> cndmask selects. Reflected rows via index math. OOB
//     addresses clamped to dummy in-bounds slots, values replaced.
#define BATCH 32
#define CHAN  3
#define HH    384
#define WW    640
#define HW    (HH * WW)
#define NBX   (WW / 128)     // 5 blocks across width

__device__ __forceinline__ void do_channel(const float* __restrict__ px,
                                           const float* __restrict__ py,
                                           int i0, int i1, int i2,  // row*WW + c0
                                           int dl, int dr,          // left/right scalar offsets
                                           bool eL, bool eR,
                                           float (&acc)[4]) {
    const float inv9  = 1.0f / 9.0f;
    const float C1v   = 6.5025f;        // (0.01*255)^2
    const float C2v   = 58.5225f;       // (0.03*255)^2
    const float wssim = 0.5f * 0.85f / 3.0f;
    const float wl1   = 0.15f / 3.0f;

    float ax[4], ay[4], as_[4], ap[4], dab[4];

#pragma unroll
    for (int r = 0; r < 3; r++) {
        const int ib = (r == 0) ? i0 : (r == 1) ? i1 : i2;
        float4 xm = *(const float4*)(px + ib);   // global_load_dwordx4
        float4 ym = *(const float4*)(py + ib);
        float xl = px[ib + dl], xr = px[ib + dr];
        float yl = py[ib + dl], yr = py[ib + dr];
        if (eL) { xl = xm.y; yl = ym.y; }        // reflect(-1)=1
        if (eR) { xr = xm.z; yr = ym.z; }        // reflect(640)=638

        float x[6], y[6];
        x[0] = xl; x[1] = xm.x; x[2] = xm.y; x[3] = xm.z; x[4] = xm.w; x[5] = xr;
        y[0] = yl; y[1] = ym.x; y[2] = ym.y; y[3] = ym.z; y[4] = ym.w; y[5] = yr;

        float ss[6], pp[6];
#pragma unroll
        for (int i = 0; i < 6; i++) {
            ss[i] = fmaf(x[i], x[i], y[i] * y[i]);
            pp[i] = x[i] * y[i];
        }
#pragma unroll
        for (int i = 0; i < 4; i++) {
            float hx = x[i]  + x[i + 1]  + x[i + 2];
            float hy = y[i]  + y[i + 1]  + y[i + 2];
            float hs = ss[i] + ss[i + 1] + ss[i + 2];
            float hp = pp[i] + pp[i + 1] + pp[i + 2];
            if (r == 0) { ax[i] = hx;  ay[i] = hy;  as_[i] = hs;  ap[i] = hp; }
            else        { ax[i] += hx; ay[i] += hy; as_[i] += hs; ap[i] += hp; }
        }
        if (r == 1) {
#pragma unroll
            for (int k = 0; k < 4; k++) {
                float xv = (k == 0) ? xm.x : (k == 1) ? xm.y : (k == 2) ? xm.z : xm.w;
                float yv = (k == 0) ? ym.x : (k == 1) ? ym.y : (k == 2) ? ym.z : ym.w;
                dab[k] = fabsf(xv - yv);
            }
        }
    }

#pragma unroll
    for (int k = 0; k < 4; k++) {
        float mux = ax[k] * inv9;
        float muy = ay[k] * inv9;
        float mm  = mux * muy;
        float sigsum = fmaf(as_[k], inv9, -(mux + muy));   // faithful: -mu, not -mu^2
        float sigxy  = fmaf(ap[k], inv9, -mm);
        float num = fmaf(2.0f, mm, C1v) * fmaf(2.0f, sigxy, C2v);
        float den = fmaf(muy, muy, fmaf(mux, mux, C1v)) * (sigsum + C2v);
        float q   = num * __builtin_amdgcn_rcpf(den);
        float ns  = fmaf(q, -0.5f, 0.5f);
        ns = fminf(fmaxf(ns, 0.0f), 1.0f);
        acc[k] = fmaf(wssim, ns, fmaf(wl1, dab[k], acc[k]));
    }
}

__global__ __launch_bounds__(256, 8)
void ssim_l1_kernel(const float* __restrict__ src,
                    const float* __restrict__ tgt,
                    float* __restrict__ out) {
    const int tx = threadIdx.x;          // 0..31
    const int ty = threadIdx.y;          // 0..7
    const int bx = blockIdx.x, by = blockIdx.y, b = blockIdx.z;

    const int c0 = bx * 128 + 4 * tx;    // first output col (16B aligned)
    const int oh = by * 8 + ty;          // output row

    // Window rows with height reflection.
    int r0 = oh - 1; if (r0 < 0)   r0 = 1;        // oh==0   -> reflect(-1)=1
    int r2 = oh + 1; if (r2 >= HH) r2 = HH - 2;   // oh==383 -> reflect(384)=382

    const bool eL = (bx == 0) && (tx == 0);
    const bool eR = (bx == NBX - 1) && (tx == 31);
    const int dl = eL ? 0 : -1;          // dummy in-bounds slot for edge lane
    const int dr = eR ? 0 : 4;           // (value replaced by cndmask select)

    const int i0 = r0 * WW + c0;
    const int i1 = oh * WW + c0;
    const int i2 = r2 * WW + c0;

    const float* __restrict__ sb = src + (size_t)b * CHAN * HW;
    const float* __restrict__ tb = tgt + (size_t)b * CHAN * HW;

    float acc[4] = {0.f, 0.f, 0.f, 0.f};

#pragma unroll
    for (int c = 0; c < CHAN; c++) {
        do_channel(sb + c * HW, tb + c * HW, i0, i1, i2, dl, dr, eL, eR, acc);
    }

    *(float4*)(out + ((size_t)b * HH + oh) * WW + c0) =
        make_float4(acc[0], acc[1], acc[2], acc[3]);
}

extern "C" void kernel_launch(void* const* d_in, const int* in_sizes, int n_in,
                              void* d_out, int out_size, void* d_ws, size_t ws_size,
                              hipStream_t stream) {
    const float* src = (const float*)d_in[0];   // 'output'
    const float* tgt = (const float*)d_in[1];   // 'target'
    float* out = (float*)d_out;

    dim3 grid(NBX, HH / 8, BATCH);              // (5, 48, 32) = 7680 blocks
    dim3 block(32, 8);
    ssim_l1_kernel<<<grid, block, 0, stream>>>(src, tgt, out);
}

// Round 5
// 471.989 us; speedup vs baseline: 2.0298x; 2.0298x over previous
//
#include <hip/hip_runtime.h>

// (32, 3, 384, 640) fp32 in, (32, 1, 384, 640) fp32 out.
// v6 = v5 (LDS-free register stencil) with the register cap FIXED.
// v5 post-mortem: __launch_bounds__(256,8) capped VGPR at 32 -> massive
// scratch spill (WRITE_SIZE 30MB -> 1.7GB, VALUBusy 5%, dur 10x). The
// LDS-free structure itself delivered what it promised (LDS=0, conflicts=0,
// occupancy 83%). Fix: __launch_bounds__(256,4) -> VGPR cap 128; compiler
// lands ~64 (v3/v4 used 64 for a more complex body), zero spill, and at
// <=64 VGPR the HW still reaches 8 waves/SIMD with no barriers to convoy.
//   - each thread: ONE output row x 4 px; 3 rows x 2 tensors x
//     (float4 + left/right scalar) direct from global; vertical overlap
//     between thread rows is L1/L2-served (~10KB/channel per block).
//   - zero __syncthreads, zero LDS.
//   - reflection: the only reflected COLUMNS live inside the lane's own
//     float4 (reflect(-1)=1 -> xm.y; reflect(640)=638 -> xm.z) -> selects.
//     Reflected ROWS via index math. Edge lanes' scalar addresses clamped
//     in-bounds; values replaced by the select.
#define BATCH 32
#define CHAN  3
#define HH    384
#define WW    640
#define HW    (HH * WW)
#define NBX   (WW / 128)     // 5 blocks across width

__device__ __forceinline__ void do_channel(const float* __restrict__ px,
                                           const float* __restrict__ py,
                                           int i0, int i1, int i2,  // row*WW + c0
                                           int dl, int dr,          // left/right scalar offsets
                                           bool eL, bool eR,
                                           float (&acc)[4]) {
    const float inv9  = 1.0f / 9.0f;
    const float C1v   = 6.5025f;        // (0.01*255)^2
    const float C2v   = 58.5225f;       // (0.03*255)^2
    const float wssim = 0.5f * 0.85f / 3.0f;
    const float wl1   = 0.15f / 3.0f;

    float ax[4], ay[4], as_[4], ap[4], dab[4];

#pragma unroll
    for (int r = 0; r < 3; r++) {
        const int ib = (r == 0) ? i0 : (r == 1) ? i1 : i2;
        float4 xm = *(const float4*)(px + ib);   // global_load_dwordx4
        float4 ym = *(const float4*)(py + ib);
        float xl = px[ib + dl], xr = px[ib + dr];
        float yl = py[ib + dl], yr = py[ib + dr];
        if (eL) { xl = xm.y; yl = ym.y; }        // reflect(-1)=1
        if (eR) { xr = xm.z; yr = ym.z; }        // reflect(640)=638

        float x[6], y[6];
        x[0] = xl; x[1] = xm.x; x[2] = xm.y; x[3] = xm.z; x[4] = xm.w; x[5] = xr;
        y[0] = yl; y[1] = ym.x; y[2] = ym.y; y[3] = ym.z; y[4] = ym.w; y[5] = yr;

        float ss[6], pp[6];
#pragma unroll
        for (int i = 0; i < 6; i++) {
            ss[i] = fmaf(x[i], x[i], y[i] * y[i]);
            pp[i] = x[i] * y[i];
        }
#pragma unroll
        for (int i = 0; i < 4; i++) {
            float hx = x[i]  + x[i + 1]  + x[i + 2];
            float hy = y[i]  + y[i + 1]  + y[i + 2];
            float hs = ss[i] + ss[i + 1] + ss[i + 2];
            float hp = pp[i] + pp[i + 1] + pp[i + 2];
            if (r == 0) { ax[i] = hx;  ay[i] = hy;  as_[i] = hs;  ap[i] = hp; }
            else        { ax[i] += hx; ay[i] += hy; as_[i] += hs; ap[i] += hp; }
        }
        if (r == 1) {
#pragma unroll
            for (int k = 0; k < 4; k++) {
                float xv = (k == 0) ? xm.x : (k == 1) ? xm.y : (k == 2) ? xm.z : xm.w;
                float yv = (k == 0) ? ym.x : (k == 1) ? ym.y : (k == 2) ? ym.z : ym.w;
                dab[k] = fabsf(xv - yv);
            }
        }
    }

#pragma unroll
    for (int k = 0; k < 4; k++) {
        float mux = ax[k] * inv9;
        float muy = ay[k] * inv9;
        float mm  = mux * muy;
        float sigsum = fmaf(as_[k], inv9, -(mux + muy));   // faithful: -mu, not -mu^2
        float sigxy  = fmaf(ap[k], inv9, -mm);
        float num = fmaf(2.0f, mm, C1v) * fmaf(2.0f, sigxy, C2v);
        float den = fmaf(muy, muy, fmaf(mux, mux, C1v)) * (sigsum + C2v);
        float q   = num * __builtin_amdgcn_rcpf(den);
        float ns  = fmaf(q, -0.5f, 0.5f);
        ns = fminf(fmaxf(ns, 0.0f), 1.0f);
        acc[k] = fmaf(wssim, ns, fmaf(wl1, dab[k], acc[k]));
    }
}

__global__ __launch_bounds__(256, 4)
void ssim_l1_kernel(const float* __restrict__ src,
                    const float* __restrict__ tgt,
                    float* __restrict__ out) {
    const int tx = threadIdx.x;          // 0..31
    const int ty = threadIdx.y;          // 0..7
    const int bx = blockIdx.x, by = blockIdx.y, b = blockIdx.z;

    const int c0 = bx * 128 + 4 * tx;    // first output col (16B aligned)
    const int oh = by * 8 + ty;          // output row

    // Window rows with height reflection.
    int r0 = oh - 1; if (r0 < 0)   r0 = 1;        // oh==0   -> reflect(-1)=1
    int r2 = oh + 1; if (r2 >= HH) r2 = HH - 2;   // oh==383 -> reflect(384)=382

    const bool eL = (bx == 0) && (tx == 0);
    const bool eR = (bx == NBX - 1) && (tx == 31);
    const int dl = eL ? 0 : -1;          // in-bounds dummy for edge lanes
    const int dr = eR ? 0 : 4;           // (value replaced by the select)

    const int i0 = r0 * WW + c0;
    const int i1 = oh * WW + c0;
    const int i2 = r2 * WW + c0;

    const float* __restrict__ sb = src + (size_t)b * CHAN * HW;
    const float* __restrict__ tb = tgt + (size_t)b * CHAN * HW;

    float acc[4] = {0.f, 0.f, 0.f, 0.f};

#pragma unroll
    for (int c = 0; c < CHAN; c++) {
        do_channel(sb + c * HW, tb + c * HW, i0, i1, i2, dl, dr, eL, eR, acc);
    }

    *(float4*)(out + ((size_t)b * HH + oh) * WW + c0) =
        make_float4(acc[0], acc[1], acc[2], acc[3]);
}

extern "C" void kernel_launch(void* const* d_in, const int* in_sizes, int n_in,
                              void* d_out, int out_size, void* d_ws, size_t ws_size,
                              hipStream_t stream) {
    const float* src = (const float*)d_in[0];   // 'output'
    const float* tgt = (const float*)d_in[1];   // 'target'
    float* out = (float*)d_out;

    dim3 grid(NBX, HH / 8, BATCH);              // (5, 48, 32) = 7680 blocks
    dim3 block(32, 8);
    ssim_l1_kernel<<<grid, block, 0, stream>>>(src, tgt, out);
}

// Round 6
// 325.056 us; speedup vs baseline: 2.9473x; 1.4520x over previous
//
#include <hip/hip_runtime.h>

// (32, 3, 384, 640) fp32 in, (32, 1, 384, 640) fp32 out.
// v7: LDS-free register stencil, NO launch_bounds, 2 output rows/thread.
// v5/v6 post-mortem: __launch_bounds__ 2nd arg empirically caps VGPR at
// 256/arg on this toolchain (v5 (256,8)->32, v6 (256,4)->64), strangling
// the body into scratch spill (WRITE_SIZE 599MB vs 31MB output). Fix: no
// launch_bounds at all -> allocator takes ~90-120 regs, zero spill;
// ~5 waves/SIMD occupancy with zero barriers to convoy them.
//   - each thread: TWO output rows x 4 px. 4 loaded rows serve both
//     windows (rows/px 3 -> 2: 33% less load traffic), shared rows'
//     x^2/y^2/xy computed once (v4's verified two-window accumulate).
//   - zero __syncthreads, zero LDS; vertical overlap served by L1/L2.
//   - reflection: reflected COLUMNS live inside the lane's own float4
//     (reflect(-1)=1 -> .y; reflect(640)=638 -> .z) -> selects; reflected
//     ROWS via index math; edge lanes' scalar addrs clamped in-bounds.
#define BATCH 32
#define CHAN  3
#define HH    384
#define WW    640
#define HW    (HH * WW)
#define NBX   (WW / 128)     // 5
#define NBY   (HH / 16)      // 24

__global__ void ssim_l1_kernel(const float* __restrict__ src,
                               const float* __restrict__ tgt,
                               float* __restrict__ out) {
    const int tx = threadIdx.x;          // 0..31
    const int ty = threadIdx.y;          // 0..7
    const int bx = blockIdx.x, by = blockIdx.y, b = blockIdx.z;

    const int c0  = bx * 128 + 4 * tx;   // first output col (16B aligned)
    const int oh0 = by * 16 + 2 * ty;    // first of this thread's 2 output rows

    // 4 input rows (with height reflection at the global edges).
    const int r0 = (oh0 == 0) ? 1 : oh0 - 1;          // reflect(-1)=1
    const int r1 = oh0;
    const int r2 = oh0 + 1;
    const int r3 = (oh0 + 2 >= HH) ? HH - 2 : oh0 + 2; // reflect(384)=382

    const bool eL = (bx == 0) && (tx == 0);
    const bool eR = (bx == NBX - 1) && (tx == 31);
    const int dl = eL ? 0 : -1;          // in-bounds dummy for edge lanes
    const int dr = eR ? 0 : 4;           // (value replaced by the select)

    const int i0 = r0 * WW + c0;
    const int i1 = r1 * WW + c0;
    const int i2 = r2 * WW + c0;
    const int i3 = r3 * WW + c0;

    const float* __restrict__ sb = src + (size_t)b * CHAN * HW;
    const float* __restrict__ tb = tgt + (size_t)b * CHAN * HW;

    const float inv9  = 1.0f / 9.0f;
    const float C1v   = 6.5025f;         // (0.01*255)^2
    const float C2v   = 58.5225f;        // (0.03*255)^2
    const float wssim = 0.5f * 0.85f / 3.0f;
    const float wl1   = 0.15f / 3.0f;

    float acc0[4] = {0.f, 0.f, 0.f, 0.f};
    float acc1[4] = {0.f, 0.f, 0.f, 0.f};

#pragma unroll 1
    for (int c = 0; c < CHAN; c++) {
        const float* __restrict__ px = sb + c * HW;
        const float* __restrict__ py = tb + c * HW;

        float a0x[4], a0y[4], a0s[4], a0p[4];   // window rows r0..r2 (out oh0)
        float a1x[4], a1y[4], a1s[4], a1p[4];   // window rows r1..r3 (out oh0+1)
        float dab0[4], dab1[4];

#pragma unroll
        for (int rr = 0; rr < 4; rr++) {
            const int ib = (rr == 0) ? i0 : (rr == 1) ? i1 : (rr == 2) ? i2 : i3;
            float4 xm = *(const float4*)(px + ib);   // global_load_dwordx4
            float4 ym = *(const float4*)(py + ib);
            float xl = px[ib + dl], xr = px[ib + dr];
            float yl = py[ib + dl], yr = py[ib + dr];
            if (eL) { xl = xm.y; yl = ym.y; }        // reflect(-1)=1
            if (eR) { xr = xm.z; yr = ym.z; }        // reflect(640)=638

            float x[6], y[6];
            x[0] = xl; x[1] = xm.x; x[2] = xm.y; x[3] = xm.z; x[4] = xm.w; x[5] = xr;
            y[0] = yl; y[1] = ym.x; y[2] = ym.y; y[3] = ym.z; y[4] = ym.w; y[5] = yr;

            float ss[6], pp[6];
#pragma unroll
            for (int i = 0; i < 6; i++) {
                ss[i] = fmaf(x[i], x[i], y[i] * y[i]);
                pp[i] = x[i] * y[i];
            }
#pragma unroll
            for (int i = 0; i < 4; i++) {
                float hx = x[i]  + x[i + 1]  + x[i + 2];
                float hy = y[i]  + y[i + 1]  + y[i + 2];
                float hs = ss[i] + ss[i + 1] + ss[i + 2];
                float hp = pp[i] + pp[i + 1] + pp[i + 2];
                if (rr == 0) {
                    a0x[i] = hx;  a0y[i] = hy;  a0s[i] = hs;  a0p[i] = hp;
                } else if (rr == 1) {
                    a0x[i] += hx; a0y[i] += hy; a0s[i] += hs; a0p[i] += hp;
                    a1x[i] = hx;  a1y[i] = hy;  a1s[i] = hs;  a1p[i] = hp;
                } else if (rr == 2) {
                    a0x[i] += hx; a0y[i] += hy; a0s[i] += hs; a0p[i] += hp;
                    a1x[i] += hx; a1y[i] += hy; a1s[i] += hs; a1p[i] += hp;
                } else {
                    a1x[i] += hx; a1y[i] += hy; a1s[i] += hs; a1p[i] += hp;
                }
            }
            if (rr == 1) {   // middle row of window A = output row oh0
#pragma unroll
                for (int k = 0; k < 4; k++) {
                    float xv = (k == 0) ? xm.x : (k == 1) ? xm.y : (k == 2) ? xm.z : xm.w;
                    float yv = (k == 0) ? ym.x : (k == 1) ? ym.y : (k == 2) ? ym.z : ym.w;
                    dab0[k] = fabsf(xv - yv);
                }
            }
            if (rr == 2) {   // middle row of window B = output row oh0+1
#pragma unroll
                for (int k = 0; k < 4; k++) {
                    float xv = (k == 0) ? xm.x : (k == 1) ? xm.y : (k == 2) ? xm.z : xm.w;
                    float yv = (k == 0) ? ym.x : (k == 1) ? ym.y : (k == 2) ? ym.z : ym.w;
                    dab1[k] = fabsf(xv - yv);
                }
            }
        }

#pragma unroll
        for (int k = 0; k < 4; k++) {
            float mux = a0x[k] * inv9;
            float muy = a0y[k] * inv9;
            float mm  = mux * muy;
            float sigsum = fmaf(a0s[k], inv9, -(mux + muy));   // faithful: -mu
            float sigxy  = fmaf(a0p[k], inv9, -mm);
            float num = fmaf(2.0f, mm, C1v) * fmaf(2.0f, sigxy, C2v);
            float den = fmaf(muy, muy, fmaf(mux, mux, C1v)) * (sigsum + C2v);
            float q   = num * __builtin_amdgcn_rcpf(den);
            float ns  = fmaf(q, -0.5f, 0.5f);
            ns = fminf(fmaxf(ns, 0.0f), 1.0f);
            acc0[k] = fmaf(wssim, ns, fmaf(wl1, dab0[k], acc0[k]));
        }
#pragma unroll
        for (int k = 0; k < 4; k++) {
            float mux = a1x[k] * inv9;
            float muy = a1y[k] * inv9;
            float mm  = mux * muy;
            float sigsum = fmaf(a1s[k], inv9, -(mux + muy));
            float sigxy  = fmaf(a1p[k], inv9, -mm);
            float num = fmaf(2.0f, mm, C1v) * fmaf(2.0f, sigxy, C2v);
            float den = fmaf(muy, muy, fmaf(mux, mux, C1v)) * (sigsum + C2v);
            float q   = num * __builtin_amdgcn_rcpf(den);
            float ns  = fmaf(q, -0.5f, 0.5f);
            ns = fminf(fmaxf(ns, 0.0f), 1.0f);
            acc1[k] = fmaf(wssim, ns, fmaf(wl1, dab1[k], acc1[k]));
        }
    }

    float4* o0 = (float4*)(out + ((size_t)b * HH + oh0)     * WW + c0);
    float4* o1 = (float4*)(out + ((size_t)b * HH + oh0 + 1) * WW + c0);
    *o0 = make_float4(acc0[0], acc0[1], acc0[2], acc0[3]);
    *o1 = make_float4(acc1[0], acc1[1], acc1[2], acc1[3]);
}

extern "C" void kernel_launch(void* const* d_in, const int* in_sizes, int n_in,
                              void* d_out, int out_size, void* d_ws, size_t ws_size,
                              hipStream_t stream) {
    const float* src = (const float*)d_in[0];   // 'output'
    const float* tgt = (const float*)d_in[1];   // 'target'
    float* out = (float*)d_out;

    dim3 grid(NBX, NBY, BATCH);                 // (5, 24, 32) = 3840 blocks
    dim3 block(32, 8);
    ssim_l1_kernel<<<grid, block, 0, stream>>>(src, tgt, out);
}

// Round 7
// 219.760 us; speedup vs baseline: 4.3594x; 1.4791x over previous
//
#include <hip/hip_runtime.h>

// (32, 3, 384, 640) fp32 in, (32, 1, 384, 640) fp32 out.
// v8 = v7 (LDS-free register stencil, 2 output rows/thread) with the
// register-cap rule finally applied correctly.
// Empirical toolchain rule (v1/v3/v5/v6/v7 ladder): VGPR cap = 256/min_waves
// (granule 8); with NO launch_bounds the heuristic still targets 64 and
// SPILLS the difference (v7: 146MB scratch traffic, VALUBusy 17%).
// Fix: __launch_bounds__(256, 2) -> cap 128. Body peak ~100-125 regs ->
// zero spill; <=128 VGPR still gives 16 waves/CU (4/SIMD, same as v3) with
// ZERO barriers and 33% fewer loaded bytes than the 1-row variant.
//   - each thread: TWO output rows x 4 px; 4 loaded rows serve both
//     3-row windows; shared rows' x^2/y^2/xy computed once.
//   - zero __syncthreads, zero LDS; vertical overlap served by L1/L2.
//   - reflection: reflected COLUMNS live inside the lane's own float4
//     (reflect(-1)=1 -> .y; reflect(640)=638 -> .z) -> selects; reflected
//     ROWS via index math; edge lanes' scalar addrs clamped in-bounds.
#define BATCH 32
#define CHAN  3
#define HH    384
#define WW    640
#define HW    (HH * WW)
#define NBX   (WW / 128)     // 5
#define NBY   (HH / 16)      // 24

__global__ __launch_bounds__(256, 2)
void ssim_l1_kernel(const float* __restrict__ src,
                    const float* __restrict__ tgt,
                    float* __restrict__ out) {
    const int tx = threadIdx.x;          // 0..31
    const int ty = threadIdx.y;          // 0..7
    const int bx = blockIdx.x, by = blockIdx.y, b = blockIdx.z;

    const int c0  = bx * 128 + 4 * tx;   // first output col (16B aligned)
    const int oh0 = by * 16 + 2 * ty;    // first of this thread's 2 output rows

    // 4 input rows (with height reflection at the global edges).
    const int r0 = (oh0 == 0) ? 1 : oh0 - 1;           // reflect(-1)=1
    const int r1 = oh0;
    const int r2 = oh0 + 1;
    const int r3 = (oh0 + 2 >= HH) ? HH - 2 : oh0 + 2; // reflect(384)=382

    const bool eL = (bx == 0) && (tx == 0);
    const bool eR = (bx == NBX - 1) && (tx == 31);
    const int dl = eL ? 0 : -1;          // in-bounds dummy for edge lanes
    const int dr = eR ? 0 : 4;           // (value replaced by the select)

    const int i0 = r0 * WW + c0;
    const int i1 = r1 * WW + c0;
    const int i2 = r2 * WW + c0;
    const int i3 = r3 * WW + c0;

    const float* __restrict__ sb = src + (size_t)b * CHAN * HW;
    const float* __restrict__ tb = tgt + (size_t)b * CHAN * HW;

    const float inv9  = 1.0f / 9.0f;
    const float C1v   = 6.5025f;         // (0.01*255)^2
    const float C2v   = 58.5225f;        // (0.03*255)^2
    const float wssim = 0.5f * 0.85f / 3.0f;
    const float wl1   = 0.15f / 3.0f;

    float acc0[4] = {0.f, 0.f, 0.f, 0.f};
    float acc1[4] = {0.f, 0.f, 0.f, 0.f};

#pragma unroll 1
    for (int c = 0; c < CHAN; c++) {
        const float* __restrict__ px = sb + c * HW;
        const float* __restrict__ py = tb + c * HW;

        float a0x[4], a0y[4], a0s[4], a0p[4];   // window rows r0..r2 (out oh0)
        float a1x[4], a1y[4], a1s[4], a1p[4];   // window rows r1..r3 (out oh0+1)
        float dab0[4], dab1[4];

#pragma unroll
        for (int rr = 0; rr < 4; rr++) {
            const int ib = (rr == 0) ? i0 : (rr == 1) ? i1 : (rr == 2) ? i2 : i3;
            float4 xm = *(const float4*)(px + ib);   // global_load_dwordx4
            float4 ym = *(const float4*)(py + ib);
            float xl = px[ib + dl], xr = px[ib + dr];
            float yl = py[ib + dl], yr = py[ib + dr];
            if (eL) { xl = xm.y; yl = ym.y; }        // reflect(-1)=1
            if (eR) { xr = xm.z; yr = ym.z; }        // reflect(640)=638

            float x[6], y[6];
            x[0] = xl; x[1] = xm.x; x[2] = xm.y; x[3] = xm.z; x[4] = xm.w; x[5] = xr;
            y[0] = yl; y[1] = ym.x; y[2] = ym.y; y[3] = ym.z; y[4] = ym.w; y[5] = yr;

            float ss[6], pp[6];
#pragma unroll
            for (int i = 0; i < 6; i++) {
                ss[i] = fmaf(x[i], x[i], y[i] * y[i]);
                pp[i] = x[i] * y[i];
            }
#pragma unroll
            for (int i = 0; i < 4; i++) {
                float hx = x[i]  + x[i + 1]  + x[i + 2];
                float hy = y[i]  + y[i + 1]  + y[i + 2];
                float hs = ss[i] + ss[i + 1] + ss[i + 2];
                float hp = pp[i] + pp[i + 1] + pp[i + 2];
                if (rr == 0) {
                    a0x[i] = hx;  a0y[i] = hy;  a0s[i] = hs;  a0p[i] = hp;
                } else if (rr == 1) {
                    a0x[i] += hx; a0y[i] += hy; a0s[i] += hs; a0p[i] += hp;
                    a1x[i] = hx;  a1y[i] = hy;  a1s[i] = hs;  a1p[i] = hp;
                } else if (rr == 2) {
                    a0x[i] += hx; a0y[i] += hy; a0s[i] += hs; a0p[i] += hp;
                    a1x[i] += hx; a1y[i] += hy; a1s[i] += hs; a1p[i] += hp;
                } else {
                    a1x[i] += hx; a1y[i] += hy; a1s[i] += hs; a1p[i] += hp;
                }
            }
            if (rr == 1) {   // middle row of window A = output row oh0
#pragma unroll
                for (int k = 0; k < 4; k++) {
                    float xv = (k == 0) ? xm.x : (k == 1) ? xm.y : (k == 2) ? xm.z : xm.w;
                    float yv = (k == 0) ? ym.x : (k == 1) ? ym.y : (k == 2) ? ym.z : ym.w;
                    dab0[k] = fabsf(xv - yv);
                }
            }
            if (rr == 2) {   // middle row of window B = output row oh0+1
#pragma unroll
                for (int k = 0; k < 4; k++) {
                    float xv = (k == 0) ? xm.x : (k == 1) ? xm.y : (k == 2) ? xm.z : xm.w;
                    float yv = (k == 0) ? ym.x : (k == 1) ? ym.y : (k == 2) ? ym.z : ym.w;
                    dab1[k] = fabsf(xv - yv);
                }
            }
        }

#pragma unroll
        for (int k = 0; k < 4; k++) {
            float mux = a0x[k] * inv9;
            float muy = a0y[k] * inv9;
            float mm  = mux * muy;
            float sigsum = fmaf(a0s[k], inv9, -(mux + muy));   // faithful: -mu
            float sigxy  = fmaf(a0p[k], inv9, -mm);
            float num = fmaf(2.0f, mm, C1v) * fmaf(2.0f, sigxy, C2v);
            float den = fmaf(muy, muy, fmaf(mux, mux, C1v)) * (sigsum + C2v);
            float q   = num * __builtin_amdgcn_rcpf(den);
            float ns  = fmaf(q, -0.5f, 0.5f);
            ns = fminf(fmaxf(ns, 0.0f), 1.0f);
            acc0[k] = fmaf(wssim, ns, fmaf(wl1, dab0[k], acc0[k]));
        }
#pragma unroll
        for (int k = 0; k < 4; k++) {
            float mux = a1x[k] * inv9;
            float muy = a1y[k] * inv9;
            float mm  = mux * muy;
            float sigsum = fmaf(a1s[k], inv9, -(mux + muy));
            float sigxy  = fmaf(a1p[k], inv9, -mm);
            float num = fmaf(2.0f, mm, C1v) * fmaf(2.0f, sigxy, C2v);
            float den = fmaf(muy, muy, fmaf(mux, mux, C1v)) * (sigsum + C2v);
            float q   = num * __builtin_amdgcn_rcpf(den);
            float ns  = fmaf(q, -0.5f, 0.5f);
            ns = fminf(fmaxf(ns, 0.0f), 1.0f);
            acc1[k] = fmaf(wssim, ns, fmaf(wl1, dab1[k], acc1[k]));
        }
    }

    float4* o0 = (float4*)(out + ((size_t)b * HH + oh0)     * WW + c0);
    float4* o1 = (float4*)(out + ((size_t)b * HH + oh0 + 1) * WW + c0);
    *o0 = make_float4(acc0[0], acc0[1], acc0[2], acc0[3]);
    *o1 = make_float4(acc1[0], acc1[1], acc1[2], acc1[3]);
}

extern "C" void kernel_launch(void* const* d_in, const int* in_sizes, int n_in,
                              void* d_out, int out_size, void* d_ws, size_t ws_size,
                              hipStream_t stream) {
    const float* src = (const float*)d_in[0];   // 'output'
    const float* tgt = (const float*)d_in[1];   // 'target'
    float* out = (float*)d_out;

    dim3 grid(NBX, NBY, BATCH);                 // (5, 24, 32) = 3840 blocks
    dim3 block(32, 8);
    ssim_l1_kernel<<<grid, block, 0, stream>>>(src, tgt, out);
}